// Round 9
// baseline (1385.145 us; speedup 1.0000x reference)
//
#include <hip/hip_runtime.h>
#include <cstdint>
#include <cstddef>

#define N_  8
#define C_  256
#define HW_ 1024
#define CL_ 16
#define SZ_ (N_*C_*HW_)   // 2,097,152 elements per tensor
#define WSCALE_ 4096.0f   // 2^12 exact; folded into A, cancels in L2-norm

typedef __attribute__((ext_vector_type(8))) _Float16 half8;
typedef __attribute__((ext_vector_type(4))) float f32x4;

static __device__ __forceinline__ float tanh_fast(float x){
  x = fminf(fmaxf(x, -15.f), 15.f);
  float e = __expf(2.f * x);
  return (e - 1.f) / (e + 1.f);
}

static __device__ __forceinline__ unsigned short f2h(float x){
  _Float16 h = (_Float16)x;
  return *(unsigned short*)&h;
}

static __device__ __forceinline__ void combine16(
    const float* __restrict__ mpart, const float* __restrict__ spart,
    int base, float& m, float& rl)
{
  m = -1e30f;
  #pragma unroll
  for (int k = 0; k < 16; ++k) m = fmaxf(m, mpart[base * 16 + k]);
  float s = 0.f;
  #pragma unroll
  for (int k = 0; k < 16; ++k) s += spart[base * 16 + k] * __expf(mpart[base * 16 + k] - m);
  rl = 1.f / s;
}

#define GLD16(g, l) __builtin_amdgcn_global_load_lds( \
    (const __attribute__((address_space(1))) void*)(g), \
    (__attribute__((address_space(3))) void*)(l), 16, 0, 0)

// Persistent fused kernel: 256 blocks x 512 threads, 1 block/CU.
// Blocks 32n..32n+31 form group n; phases sync via per-n device-scope barrier.
// Per iteration: A = sa-dot + softmax partials; B = corr (A/At w-folded fp16);
// C = MFMA GEMM + L2-norm + residual/ReLU (+ h/s outputs at last iter).
__global__ __launch_bounds__(512, 4) void k_all(
    const float* __restrict__ f1, const float* __restrict__ f2,
    const float* __restrict__ pw1, const float* __restrict__ pb1,
    const float* __restrict__ pw2, const float* __restrict__ pb2,
    const float* __restrict__ cw1, const float* __restrict__ cw2,
    float* __restrict__ out, float* __restrict__ ws)
{
  // workspace layout (floats)
  float* cval  = ws;                           // 16384
  float* pdot  = cval + 16384;                 // 262144
  float* mpart = pdot + 262144;                // 512
  float* spart = mpart + 512;                  // 512
  float* fp1   = spart + 512;                  // SZ_
  float* fp2   = fp1 + SZ_;                    // SZ_
  _Float16* fhA1 = (_Float16*)(fp2 + SZ_);     // SZ_ halves each
  _Float16* fhA2 = fhA1 + SZ_;
  _Float16* fhB1 = fhA2 + SZ_;
  _Float16* fhB2 = fhB1 + SZ_;
  unsigned short* Abf  = (unsigned short*)(fhB2 + SZ_);   // 8M halves
  unsigned short* Atbf = Abf + ((size_t)N_ << 20);        // 8M halves
  unsigned* barc = (unsigned*)(Atbf + ((size_t)N_ << 20)); // 8 counters, stride 16u

  __shared__ __align__(16) unsigned char pool[81920];  // phase-overlaid

  const int b = blockIdx.x, t = threadIdx.x;
  const int nb = b >> 5;                        // group n (same for all phases)
  unsigned* ctr = barc + nb * 16;
  int ep = 0;

  auto gbar = [&](){
    __syncthreads();
    ++ep;
    if (t == 0){
      __threadfence();
      __hip_atomic_fetch_add(ctr, 1u, __ATOMIC_RELEASE, __HIP_MEMORY_SCOPE_AGENT);
      const unsigned tgt = 32u * (unsigned)ep;
      while (__hip_atomic_load(ctr, __ATOMIC_ACQUIRE, __HIP_MEMORY_SCOPE_AGENT) < tgt)
        __builtin_amdgcn_s_sleep(2);
    }
    __syncthreads();
    __threadfence();
  };

  // ---- phase 0 (once): fp32 -> fp16 mirror, group-local slices ----
  {
    const int bg = b & 31;
    #pragma unroll
    for (int s = 0; s < 2; ++s){
      const size_t o = (size_t)nb * (C_ * HW_) + (size_t)bg * 8192 + s * 4096 + t * 8;
      const float4 a0 = *(const float4*)&f1[o];
      const float4 a1 = *(const float4*)&f1[o + 4];
      half8 r;
      r[0] = (_Float16)a0.x; r[1] = (_Float16)a0.y; r[2] = (_Float16)a0.z; r[3] = (_Float16)a0.w;
      r[4] = (_Float16)a1.x; r[5] = (_Float16)a1.y; r[6] = (_Float16)a1.z; r[7] = (_Float16)a1.w;
      *(half8*)&fhA1[o] = r;
      const float4 b0 = *(const float4*)&f2[o];
      const float4 b1 = *(const float4*)&f2[o + 4];
      half8 r2;
      r2[0] = (_Float16)b0.x; r2[1] = (_Float16)b0.y; r2[2] = (_Float16)b0.z; r2[3] = (_Float16)b0.w;
      r2[4] = (_Float16)b1.x; r2[5] = (_Float16)b1.y; r2[6] = (_Float16)b1.z; r2[7] = (_Float16)b1.w;
      *(half8*)&fhA2[o] = r2;
    }
  }
  // first consumer of the mirror is phase C, two barriers away — no bar needed here

  for (int it = 0; it < 5; ++it){
    const int last = (it == 4);
    const float* cur1 = it ? fp1 : f1;
    const float* cur2 = it ? fp2 : f2;
    const _Float16* fhc1 = (it & 1) ? fhB1 : fhA1;
    const _Float16* fhc2 = (it & 1) ? fhB2 : fhA2;
    _Float16* fhn1 = (it & 1) ? fhA1 : fhB1;
    _Float16* fhn2 = (it & 1) ? fhA2 : fhB2;

    // ================= phase A: sa-dot + softmax partials =================
    {
      const int side = (b >> 4) & 1, hw0 = (b & 15) * 64;
      const int hwl = t & 63, cg = t >> 6;             // 8 channel-groups x 32
      const float* __restrict__ pw = side ? pw2 : pw1;
      const float* __restrict__ cw = side ? cw2 : cw1;
      const float* __restrict__ f = (side ? cur2 : cur1) + (size_t)nb * C_ * HW_ + hw0 + hwl;
      const int cb = __builtin_amdgcn_readfirstlane(cg * 32);

      float acc[17];
      #pragma unroll
      for (int l = 0; l < 17; ++l) acc[l] = 0.f;
      for (int cc = 0; cc < 32; ++cc){
        const int c = cb + cc;
        const float v = f[(size_t)c * HW_];
        acc[16] += v * cw[c];
        #pragma unroll
        for (int l = 0; l < 16; ++l) acc[l] += v * pw[l * C_ + c];
      }
      float (*red)[8][64] = (float(*)[8][64])pool;
      #pragma unroll
      for (int l = 0; l < 17; ++l) red[l][cg][hwl] = acc[l];
      __syncthreads();
      if (t < 64){
        const int base = nb * 2 + side;
        float xc = 0.f;
        #pragma unroll
        for (int l = 0; l < 17; ++l){
          float s = 0.f;
          #pragma unroll
          for (int q = 0; q < 8; ++q) s += red[l][q][t];
          if (l < 16) pdot[((size_t)base * CL_ + l) * HW_ + hw0 + t] = s;
          else      { cval[(size_t)base * HW_ + hw0 + t] = s; xc = s; }
        }
        float mb = xc;
        #pragma unroll
        for (int off = 32; off; off >>= 1) mb = fmaxf(mb, __shfl_xor(mb, off));
        float e = __expf(xc - mb);
        #pragma unroll
        for (int off = 32; off; off >>= 1) e += __shfl_xor(e, off);
        if (t == 0){
          mpart[base * 16 + (b & 15)] = mb;
          spart[base * 16 + (b & 15)] = e;
        }
      }
    }
    gbar();

    // ================= phase B: corr -> w-folded fp16 A / At =================
    {
      const int bb1 = nb * 2, bb2 = nb * 2 + 1;
      float m1, rl1, m2, rl2;
      combine16(mpart, spart, bb1, m1, rl1);
      combine16(mpart, spart, bb2, m2, rl2);
      const int half = t >> 8, tt = t & 255;           // two 64x64 tiles in parallel
      float* s2h = (float*)(pool + half * 4096);
      float* s1h = (float*)(pool + 8192 + half * 4096);
      unsigned short (*at_h)[68] = (unsigned short (*)[68])(pool + 16384 + half * 8704);
      const int lr = tt >> 4, lc = (tt & 15) * 4;
      const int ti = tt >> 4, tj = tt & 15;
      unsigned short* __restrict__ An  = Abf  + ((size_t)nb << 20);
      unsigned short* __restrict__ Atn = Atbf + ((size_t)nb << 20);

      for (int r4 = 0; r4 < 4; ++r4){
        const int idx = (b & 31) * 8 + r4 * 2 + half;
        const int j0 = (idx >> 4) * 64, i0 = (idx & 15) * 64;

        {
          const float bias2 = pb2[lr];
          const float4 c2 = *(const float4*)&cval[(size_t)bb2 * HW_ + i0 + lc];
          const float4 p2 = *(const float4*)&pdot[((size_t)bb2 * CL_ + lr) * HW_ + i0 + lc];
          s2h[lr * 64 + lc + 0] = __expf(c2.x - m2) * rl2 * p2.x + bias2;
          s2h[lr * 64 + lc + 1] = __expf(c2.y - m2) * rl2 * p2.y + bias2;
          s2h[lr * 64 + lc + 2] = __expf(c2.z - m2) * rl2 * p2.z + bias2;
          s2h[lr * 64 + lc + 3] = __expf(c2.w - m2) * rl2 * p2.w + bias2;
          const float bias1 = pb1[lr];
          const float4 c1 = *(const float4*)&cval[(size_t)bb1 * HW_ + j0 + lc];
          const float4 p1 = *(const float4*)&pdot[((size_t)bb1 * CL_ + lr) * HW_ + j0 + lc];
          s1h[lr * 64 + lc + 0] = __expf(c1.x - m1) * rl1 * p1.x + bias1;
          s1h[lr * 64 + lc + 1] = __expf(c1.y - m1) * rl1 * p1.y + bias1;
          s1h[lr * 64 + lc + 2] = __expf(c1.z - m1) * rl1 * p1.z + bias1;
          s1h[lr * 64 + lc + 3] = __expf(c1.w - m1) * rl1 * p1.w + bias1;
        }
        __syncthreads();

        float acc[4][4];
        #pragma unroll
        for (int a = 0; a < 4; ++a)
          #pragma unroll
          for (int bq = 0; bq < 4; ++bq) acc[a][bq] = 0.f;
        #pragma unroll
        for (int l = 0; l < CL_; ++l){
          const float4 a4 = *(const float4*)&s2h[l * 64 + ti * 4];
          const float4 b4 = *(const float4*)&s1h[l * 64 + tj * 4];
          const float av[4] = {a4.x, a4.y, a4.z, a4.w};
          const float bv[4] = {b4.x, b4.y, b4.z, b4.w};
          #pragma unroll
          for (int a = 0; a < 4; ++a)
            #pragma unroll
            for (int bq = 0; bq < 4; ++bq) acc[a][bq] += av[a] * bv[bq];
        }

        float tf[4][4];
        #pragma unroll
        for (int a = 0; a < 4; ++a)
          #pragma unroll
          for (int bq = 0; bq < 4; ++bq) tf[a][bq] = tanh_fast(acc[a][bq]);

        float w1j[4], w2i[4];
        #pragma unroll
        for (int bq = 0; bq < 4; ++bq)
          w1j[bq] = WSCALE_ * __expf(cval[(size_t)bb1 * HW_ + j0 + tj * 4 + bq] - m1) * rl1;
        #pragma unroll
        for (int a = 0; a < 4; ++a)
          w2i[a] = WSCALE_ * __expf(cval[(size_t)bb2 * HW_ + i0 + ti * 4 + a] - m2) * rl2;

        #pragma unroll
        for (int a = 0; a < 4; ++a){
          ushort4 va;
          va.x = f2h(tf[a][0] * w1j[0]); va.y = f2h(tf[a][1] * w1j[1]);
          va.z = f2h(tf[a][2] * w1j[2]); va.w = f2h(tf[a][3] * w1j[3]);
          *(ushort4*)&An[(size_t)(i0 + ti * 4 + a) * HW_ + j0 + tj * 4] = va;
        }
        #pragma unroll
        for (int bq = 0; bq < 4; ++bq){
          ushort4 vb;
          vb.x = f2h(tf[0][bq] * w2i[0]); vb.y = f2h(tf[1][bq] * w2i[1]);
          vb.z = f2h(tf[2][bq] * w2i[2]); vb.w = f2h(tf[3][bq] * w2i[3]);
          *(ushort4*)&at_h[tj * 4 + bq][ti * 4] = vb;
        }
        __syncthreads();
        #pragma unroll
        for (int rep = 0; rep < 2; ++rep){
          const int idx2 = tt + rep * 256;
          const int rr = idx2 >> 3, q = (idx2 & 7) * 8;
          const ushort4 lo = *(const ushort4*)&at_h[rr][q];
          const ushort4 hi = *(const ushort4*)&at_h[rr][q + 4];
          *(ushort4*)&Atn[(size_t)(j0 + rr) * HW_ + i0 + q] = lo;
          *(ushort4*)&Atn[(size_t)(j0 + rr) * HW_ + i0 + q + 4] = hi;
        }
        __syncthreads();
      }
    }
    gbar();

    // ================= phase C: MFMA GEMM + L2-norm + resid/out =================
    {
      const int p = b >> 4, it2 = b & 15, g = p & 1;
      const int i0 = it2 * 64;
      const unsigned short* __restrict__ X =
          (const unsigned short*)((g ? fhc2 : fhc1) + (size_t)nb * C_ * HW_);
      const unsigned short* __restrict__ Bp = (g ? Atbf : Abf) + ((size_t)nb << 20);
      unsigned short* XsA = (unsigned short*)pool;            // [2][16384] elems
      unsigned short* BsA = (unsigned short*)(pool + 65536);  // [2][4096] elems
      const int w = t >> 6, l = t & 63;
      const int wr = w >> 1, wc = w & 1;

      f32x4 acc[4][2];
      #pragma unroll
      for (int fm = 0; fm < 4; ++fm)
        #pragma unroll
        for (int fn = 0; fn < 2; ++fn)
          acc[fm][fn] = (f32x4){0.f, 0.f, 0.f, 0.f};

      auto stage = [&](int buf, int k0){
        #pragma unroll
        for (int s = 0; s < 4; ++s){
          const int q = (w * 4 + s) * 64 + l;
          const int row = q >> 3;
          const int kc = (q & 7) ^ (row & 7);
          GLD16(X + (size_t)row * HW_ + k0 + kc * 8, &XsA[buf * 16384 + (w * 4 + s) * 512]);
        }
        {
          const int q = w * 64 + l;
          const int row = q >> 3;
          const int kc = (q & 7) ^ (row & 7);
          GLD16(Bp + (size_t)(i0 + row) * HW_ + k0 + kc * 8, &BsA[buf * 4096 + w * 512]);
        }
      };

      stage(0, 0);
      stage(1, 64);
      for (int kt = 0; kt < 16; ++kt){
        if (kt < 15) { asm volatile("s_waitcnt vmcnt(5)" ::: "memory"); }
        else         { asm volatile("s_waitcnt vmcnt(0)" ::: "memory"); }
        __builtin_amdgcn_sched_barrier(0);
        __builtin_amdgcn_s_barrier();
        const int cur = kt & 1;
        #pragma unroll
        for (int ks = 0; ks < 2; ++ks){
          half8 a[4], bb[2];
          #pragma unroll
          for (int fm = 0; fm < 4; ++fm){
            const int row = wr * 64 + fm * 16 + (l & 15);
            const int kc = (ks * 4 + (l >> 4)) ^ (row & 7);
            a[fm] = *(const half8*)&XsA[cur * 16384 + row * 64 + kc * 8];
          }
          #pragma unroll
          for (int fn = 0; fn < 2; ++fn){
            const int row = wc * 32 + fn * 16 + (l & 15);
            const int kc = (ks * 4 + (l >> 4)) ^ (row & 7);
            bb[fn] = *(const half8*)&BsA[cur * 4096 + row * 64 + kc * 8];
          }
          #pragma unroll
          for (int fm = 0; fm < 4; ++fm)
            #pragma unroll
            for (int fn = 0; fn < 2; ++fn)
              acc[fm][fn] = __builtin_amdgcn_mfma_f32_16x16x32_f16(a[fm], bb[fn], acc[fm][fn], 0, 0, 0);
        }
        asm volatile("s_waitcnt lgkmcnt(0)" ::: "memory");
        __builtin_amdgcn_sched_barrier(0);
        __builtin_amdgcn_s_barrier();
        __builtin_amdgcn_sched_barrier(0);
        if (kt < 14) stage(cur, (kt + 2) * 64);
      }

      // epilogue: column L2-norm over 256 channels (WSCALE_ cancels)
      float ss0 = 0.f, ss1 = 0.f;
      #pragma unroll
      for (int fm = 0; fm < 4; ++fm)
        #pragma unroll
        for (int r = 0; r < 4; ++r){
          ss0 += acc[fm][0][r] * acc[fm][0][r];
          ss1 += acc[fm][1][r] * acc[fm][1][r];
        }
      ss0 += __shfl_xor(ss0, 16); ss0 += __shfl_xor(ss0, 32);
      ss1 += __shfl_xor(ss1, 16); ss1 += __shfl_xor(ss1, 32);
      float* ssred = (float*)pool;          // overlays Xs (dead now)
      float* rinvp = (float*)(pool + 1024);
      if (l < 16){
        ssred[wr * 64 + wc * 32 + l]      = ss0;
        ssred[wr * 64 + wc * 32 + 16 + l] = ss1;
      }
      __syncthreads();
      if (t < 64){
        const float s = ssred[t] + ssred[64 + t] + ssred[128 + t] + ssred[192 + t];
        rinvp[t] = 1.f / fmaxf(sqrtf(s), 1e-12f);
      }
      __syncthreads();
      const float ri[2] = { rinvp[wc * 32 + (l & 15)], rinvp[wc * 32 + 16 + (l & 15)] };

      const float* __restrict__ fpin = (g ? cur2 : cur1) + (size_t)nb * C_ * HW_;
      float* __restrict__ fpo  = (g ? fp2 : fp1) + (size_t)nb * C_ * HW_;
      _Float16* __restrict__ fhn = (g ? fhn2 : fhn1) + (size_t)nb * C_ * HW_;
      float* __restrict__ outp = out + (size_t)g * SZ_ + (size_t)nb * C_ * HW_;
      const int rbase = (l >> 4) * 4, col = l & 15;

      if (!last){
        #pragma unroll
        for (int fm = 0; fm < 4; ++fm)
          #pragma unroll
          for (int fn = 0; fn < 2; ++fn){
            const size_t base = (size_t)(wr * 64 + fm * 16 + rbase) * HW_ + i0 + wc * 32 + fn * 16 + col;
            #pragma unroll
            for (int r = 0; r < 4; ++r){
              const float h = acc[fm][fn][r] * ri[fn];
              const float fv = fpin[base + (size_t)r * HW_] + h;
              const float rv = fv > 0.f ? fv : 0.f;
              fpo[base + (size_t)r * HW_] = rv;
              fhn[base + (size_t)r * HW_] = (_Float16)rv;
            }
          }
      } else {
        float mq, rlq;
        combine16(mpart, spart, nb * 2 + g, mq, rlq);
        float wv[2];
        #pragma unroll
        for (int fn = 0; fn < 2; ++fn)
          wv[fn] = __expf(cval[(size_t)(nb * 2 + g) * HW_ + i0 + wc * 32 + fn * 16 + col] - mq) * rlq;
        float* __restrict__ out2p = out + (size_t)(2 + g) * SZ_ + (size_t)nb * C_ * HW_;
        #pragma unroll
        for (int fm = 0; fm < 4; ++fm)
          #pragma unroll
          for (int fn = 0; fn < 2; ++fn){
            const size_t base = (size_t)(wr * 64 + fm * 16 + rbase) * HW_ + i0 + wc * 32 + fn * 16 + col;
            #pragma unroll
            for (int r = 0; r < 4; ++r){
              outp[base + (size_t)r * HW_] = acc[fm][fn][r] * ri[fn];
              out2p[base + (size_t)r * HW_] = wv[fn] * fpin[base + (size_t)r * HW_];
            }
          }
      }
    }
    if (!last) gbar();
  }
}

extern "C" void kernel_launch(void* const* d_in, const int* in_sizes, int n_in,
                              void* d_out, int out_size, void* d_ws, size_t ws_size,
                              hipStream_t stream)
{
  const float* f1  = (const float*)d_in[0];
  const float* f2  = (const float*)d_in[1];
  const float* pw1 = (const float*)d_in[2];
  const float* pb1 = (const float*)d_in[3];
  const float* pw2 = (const float*)d_in[4];
  const float* pb2 = (const float*)d_in[5];
  const float* cw1 = (const float*)d_in[6];
  const float* cw2 = (const float*)d_in[8];
  // cb1/cb2 unused: softmax is shift-invariant
  float* out = (float*)d_out;
  float* wsf = (float*)d_ws;

  // barrier counters live after all buffers: float offset 17,056,768 (byte 68,227,072)
  float* barc = wsf + 17056768;
  hipMemsetAsync(barc, 0, 512, stream);

  k_all<<<dim3(256), dim3(512), 0, stream>>>(f1, f2, pw1, pb1, pw2, pb2,
                                             cw1, cw2, out, wsf);
}

// Round 10
// 243.113 us; speedup vs baseline: 5.6975x; 5.6975x over previous
//
#include <hip/hip_runtime.h>
#include <cstdint>
#include <cstddef>

#define N_  8
#define C_  256
#define HW_ 1024
#define CL_ 16
#define SZ_ (N_*C_*HW_)   // 2,097,152 elements per tensor
#define WSCALE_ 4096.0f   // 2^12 exact; folded into A, cancels in L2-norm

typedef __attribute__((ext_vector_type(8))) _Float16 half8;
typedef __attribute__((ext_vector_type(4))) float f32x4;

static __device__ __forceinline__ float tanh_fast(float x){
  x = fminf(fmaxf(x, -15.f), 15.f);
  float e = __expf(2.f * x);
  return (e - 1.f) / (e + 1.f);
}

static __device__ __forceinline__ unsigned short f2h(float x){
  _Float16 h = (_Float16)x;
  return *(unsigned short*)&h;
}

static __device__ __forceinline__ void combine16(
    const float* __restrict__ mpart, const float* __restrict__ spart,
    int base, float& m, float& rl)
{
  m = -1e30f;
  #pragma unroll
  for (int k = 0; k < 16; ++k) m = fmaxf(m, mpart[base * 16 + k]);
  float s = 0.f;
  #pragma unroll
  for (int k = 0; k < 16; ++k) s += spart[base * 16 + k] * __expf(mpart[base * 16 + k] - m);
  rl = 1.f / s;
}

#define GLD16(g, l) __builtin_amdgcn_global_load_lds( \
    (const __attribute__((address_space(1))) void*)(g), \
    (__attribute__((address_space(3))) void*)(l), 16, 0, 0)

// K0: one-time fp32 -> fp16 mirror of the input features
__global__ __launch_bounds__(256) void k_cvt(
    const float* __restrict__ f1, const float* __restrict__ f2,
    _Float16* __restrict__ o1, _Float16* __restrict__ o2)
{
  const int side = blockIdx.y;
  const size_t o = ((size_t)blockIdx.x * 256 + threadIdx.x) * 8;
  const float* __restrict__ f = side ? f2 : f1;
  _Float16* __restrict__ oo = side ? o2 : o1;
  const float4 v0 = *(const float4*)&f[o];
  const float4 v1 = *(const float4*)&f[o + 4];
  half8 r;
  r[0] = (_Float16)v0.x; r[1] = (_Float16)v0.y; r[2] = (_Float16)v0.z; r[3] = (_Float16)v0.w;
  r[4] = (_Float16)v1.x; r[5] = (_Float16)v1.y; r[6] = (_Float16)v1.z; r[7] = (_Float16)v1.w;
  *(half8*)&oo[o] = r;
}

// K1 (iteration 0 only): sa-dot on the original fp32 inputs
__global__ __launch_bounds__(256) void k_sa_dot(
    const float* __restrict__ fp1, const float* __restrict__ fp2,
    const float* __restrict__ cw1, const float* __restrict__ cw2,
    const float* __restrict__ pw1, const float* __restrict__ pw2,
    float* __restrict__ cval, float* __restrict__ pdot,
    float* __restrict__ mpart, float* __restrict__ spart)
{
  const int n = blockIdx.z, side = blockIdx.y, hw0 = blockIdx.x * 64;
  const int t = threadIdx.x, hwl = t & 63, cg = t >> 6;
  const float* __restrict__ pw = side ? pw2 : pw1;
  const float* __restrict__ cw = side ? cw2 : cw1;
  const float* __restrict__ f  = (side ? fp2 : fp1) + (size_t)n * C_ * HW_ + hw0 + hwl;
  const int cb = __builtin_amdgcn_readfirstlane(cg * 64);

  float acc[17];
  #pragma unroll
  for (int l = 0; l < 17; ++l) acc[l] = 0.f;

  for (int cc = 0; cc < 64; ++cc){
    const int c = cb + cc;
    const float v = f[(size_t)c * HW_];
    acc[16] += v * cw[c];
    #pragma unroll
    for (int l = 0; l < 16; ++l) acc[l] += v * pw[l * C_ + c];
  }

  __shared__ float red[17][4][64];
  #pragma unroll
  for (int l = 0; l < 17; ++l) red[l][cg][hwl] = acc[l];
  __syncthreads();

  if (t < 64){
    const int base = n * 2 + side;
    float xc = 0.f;
    #pragma unroll
    for (int l = 0; l < 17; ++l){
      const float s = red[l][0][t] + red[l][1][t] + red[l][2][t] + red[l][3][t];
      if (l < 16) pdot[((size_t)base * CL_ + l) * HW_ + hw0 + t] = s;
      else      { cval[(size_t)base * HW_ + hw0 + t] = s; xc = s; }
    }
    float mb = xc;
    #pragma unroll
    for (int off = 32; off; off >>= 1) mb = fmaxf(mb, __shfl_xor(mb, off));
    float e = __expf(xc - mb);
    #pragma unroll
    for (int off = 32; off; off >>= 1) e += __shfl_xor(e, off);
    if (t == 0){
      mpart[base * 16 + blockIdx.x] = mb;
      spart[base * 16 + blockIdx.x] = e;
    }
  }
}

// K2: corr -> scaled-w-folded fp16 A / At  (unchanged, validated r7)
__global__ __launch_bounds__(256) void k_corr(
    const float* __restrict__ cval, const float* __restrict__ pdot,
    const float* __restrict__ pb1, const float* __restrict__ pb2,
    const float* __restrict__ mpart, const float* __restrict__ spart,
    unsigned short* __restrict__ Abf, unsigned short* __restrict__ Atbf)
{
  const int n = blockIdx.z, i0 = blockIdx.y * 64, j0 = blockIdx.x * 64;
  const int b1 = n * 2, b2 = n * 2 + 1;
  __align__(16) __shared__ float s2[CL_][64];
  __align__(16) __shared__ float s1[CL_][64];
  __shared__ unsigned short at_s[64][68];
  const int t = threadIdx.x;
  const int lr = t >> 4, lc = (t & 15) * 4;

  float m1, rl1, m2, rl2;
  combine16(mpart, spart, b1, m1, rl1);
  combine16(mpart, spart, b2, m2, rl2);

  {
    const float bias2 = pb2[lr];
    const float4 c2 = *(const float4*)&cval[(size_t)b2 * HW_ + i0 + lc];
    const float4 p2 = *(const float4*)&pdot[((size_t)b2 * CL_ + lr) * HW_ + i0 + lc];
    s2[lr][lc + 0] = __expf(c2.x - m2) * rl2 * p2.x + bias2;
    s2[lr][lc + 1] = __expf(c2.y - m2) * rl2 * p2.y + bias2;
    s2[lr][lc + 2] = __expf(c2.z - m2) * rl2 * p2.z + bias2;
    s2[lr][lc + 3] = __expf(c2.w - m2) * rl2 * p2.w + bias2;

    const float bias1 = pb1[lr];
    const float4 c1 = *(const float4*)&cval[(size_t)b1 * HW_ + j0 + lc];
    const float4 p1 = *(const float4*)&pdot[((size_t)b1 * CL_ + lr) * HW_ + j0 + lc];
    s1[lr][lc + 0] = __expf(c1.x - m1) * rl1 * p1.x + bias1;
    s1[lr][lc + 1] = __expf(c1.y - m1) * rl1 * p1.y + bias1;
    s1[lr][lc + 2] = __expf(c1.z - m1) * rl1 * p1.z + bias1;
    s1[lr][lc + 3] = __expf(c1.w - m1) * rl1 * p1.w + bias1;
  }
  __syncthreads();

  const int ti = t >> 4, tj = t & 15;
  float acc[4][4];
  #pragma unroll
  for (int a = 0; a < 4; ++a)
    #pragma unroll
    for (int b = 0; b < 4; ++b) acc[a][b] = 0.f;

  #pragma unroll
  for (int l = 0; l < CL_; ++l){
    const float4 a4 = *(const float4*)&s2[l][ti * 4];
    const float4 b4 = *(const float4*)&s1[l][tj * 4];
    const float av[4] = {a4.x, a4.y, a4.z, a4.w};
    const float bv[4] = {b4.x, b4.y, b4.z, b4.w};
    #pragma unroll
    for (int a = 0; a < 4; ++a)
      #pragma unroll
      for (int b = 0; b < 4; ++b) acc[a][b] += av[a] * bv[b];
  }

  float tf[4][4];
  #pragma unroll
  for (int a = 0; a < 4; ++a)
    #pragma unroll
    for (int b = 0; b < 4; ++b) tf[a][b] = tanh_fast(acc[a][b]);

  float w1j[4], w2i[4];
  #pragma unroll
  for (int b = 0; b < 4; ++b)
    w1j[b] = WSCALE_ * __expf(cval[(size_t)b1 * HW_ + j0 + tj * 4 + b] - m1) * rl1;
  #pragma unroll
  for (int a = 0; a < 4; ++a)
    w2i[a] = WSCALE_ * __expf(cval[(size_t)b2 * HW_ + i0 + ti * 4 + a] - m2) * rl2;

  unsigned short* __restrict__ An  = Abf  + ((size_t)n << 20);
  unsigned short* __restrict__ Atn = Atbf + ((size_t)n << 20);
  #pragma unroll
  for (int a = 0; a < 4; ++a){
    ushort4 va;
    va.x = f2h(tf[a][0] * w1j[0]); va.y = f2h(tf[a][1] * w1j[1]);
    va.z = f2h(tf[a][2] * w1j[2]); va.w = f2h(tf[a][3] * w1j[3]);
    *(ushort4*)&An[(size_t)(i0 + ti * 4 + a) * HW_ + j0 + tj * 4] = va;
  }
  #pragma unroll
  for (int b = 0; b < 4; ++b){
    ushort4 vb;
    vb.x = f2h(tf[0][b] * w2i[0]); vb.y = f2h(tf[1][b] * w2i[1]);
    vb.z = f2h(tf[2][b] * w2i[2]); vb.w = f2h(tf[3][b] * w2i[3]);
    *(ushort4*)&at_s[tj * 4 + b][ti * 4] = vb;
  }
  __syncthreads();
  #pragma unroll
  for (int rep = 0; rep < 2; ++rep){
    const int idx = t + rep * 256;
    const int r = idx >> 3, q = (idx & 7) * 8;
    const ushort4 lo = *(const ushort4*)&at_s[r][q];
    const ushort4 hi = *(const ushort4*)&at_s[r][q + 4];
    *(ushort4*)&Atn[(size_t)(j0 + r) * HW_ + i0 + q] = lo;
    *(ushort4*)&Atn[(size_t)(j0 + r) * HW_ + i0 + q + 4] = hi;
  }
}

// K3: fused MFMA GEMM + L2-norm + residual/ReLU + NEXT-ITER sa-dot (cval/pdot/partials).
// The BM=256 block holds the full channel column of the new state in registers, so the
// conv1x1 dots for iteration it+1 are computed in-epilogue (pw staged transposed in LDS).
__global__ __launch_bounds__(512, 2) void k_gemm_fused(
    const _Float16* __restrict__ fhc1, const _Float16* __restrict__ fhc2,
    const unsigned short* __restrict__ Abf, const unsigned short* __restrict__ Atbf,
    const float* __restrict__ fpin1, const float* __restrict__ fpin2,
    float* __restrict__ fpo1, float* __restrict__ fpo2,
    _Float16* __restrict__ fhn1, _Float16* __restrict__ fhn2,
    const float* __restrict__ pw1, const float* __restrict__ pw2,
    const float* __restrict__ cw1, const float* __restrict__ cw2,
    float* __restrict__ cval, float* __restrict__ pdot,
    float* __restrict__ mpart, float* __restrict__ spart,
    float* __restrict__ out, int last)
{
  const int n = blockIdx.z, g = blockIdx.y, i0 = blockIdx.x * 64;
  const unsigned short* __restrict__ X =
      (const unsigned short*)((g ? fhc2 : fhc1) + (size_t)n * C_ * HW_);
  const unsigned short* __restrict__ B = (g ? Atbf : Abf) + ((size_t)n << 20);

  __shared__ __align__(16) unsigned char pool[81920];  // 80 KB, phase-overlaid
  // main loop:  Xs[buf] at buf*32768 (2x32KB);  Bs[buf] at 65536 + buf*8192 (2x8KB)
  // epilogue :  pwT float[256][20] at 0;  red float[4][2][2][17][16] at 32768;
  //             ssred float[4][64] at 65536;  rinv float[64] at 66560

  const int t = threadIdx.x, w = t >> 6, l = t & 63;
  const int wr = w >> 1, wc = w & 1;

  f32x4 acc[4][2];
  #pragma unroll
  for (int fm = 0; fm < 4; ++fm)
    #pragma unroll
    for (int fn = 0; fn < 2; ++fn)
      acc[fm][fn] = (f32x4){0.f, 0.f, 0.f, 0.f};

  auto stage = [&](int buf, int k0){
    unsigned short* Xsb = (unsigned short*)(pool + buf * 32768);
    unsigned short* Bsb = (unsigned short*)(pool + 65536 + buf * 8192);
    #pragma unroll
    for (int s = 0; s < 4; ++s){
      const int q = (w * 4 + s) * 64 + l;
      const int row = q >> 3;
      const int kc = (q & 7) ^ (row & 7);
      GLD16(X + (size_t)row * HW_ + k0 + kc * 8, &Xsb[(w * 4 + s) * 512]);
    }
    {
      const int q = w * 64 + l;
      const int row = q >> 3;
      const int kc = (q & 7) ^ (row & 7);
      GLD16(B + (size_t)(i0 + row) * HW_ + k0 + kc * 8, &Bsb[w * 512]);
    }
  };

  stage(0, 0);
  stage(1, 64);
  for (int kt = 0; kt < 16; ++kt){
    if (kt < 15) { asm volatile("s_waitcnt vmcnt(5)" ::: "memory"); }
    else         { asm volatile("s_waitcnt vmcnt(0)" ::: "memory"); }
    __builtin_amdgcn_sched_barrier(0);
    __builtin_amdgcn_s_barrier();
    const int cur = kt & 1;
    const unsigned short* Xsb = (const unsigned short*)(pool + cur * 32768);
    const unsigned short* Bsb = (const unsigned short*)(pool + 65536 + cur * 8192);
    #pragma unroll
    for (int ks = 0; ks < 2; ++ks){
      half8 a[4], bb[2];
      #pragma unroll
      for (int fm = 0; fm < 4; ++fm){
        const int row = wr * 64 + fm * 16 + (l & 15);
        const int kc = (ks * 4 + (l >> 4)) ^ (row & 7);
        a[fm] = *(const half8*)&Xsb[row * 64 + kc * 8];
      }
      #pragma unroll
      for (int fn = 0; fn < 2; ++fn){
        const int row = wc * 32 + fn * 16 + (l & 15);
        const int kc = (ks * 4 + (l >> 4)) ^ (row & 7);
        bb[fn] = *(const half8*)&Bsb[row * 64 + kc * 8];
      }
      #pragma unroll
      for (int fm = 0; fm < 4; ++fm)
        #pragma unroll
        for (int fn = 0; fn < 2; ++fn)
          acc[fm][fn] = __builtin_amdgcn_mfma_f32_16x16x32_f16(a[fm], bb[fn], acc[fm][fn], 0, 0, 0);
    }
    asm volatile("s_waitcnt lgkmcnt(0)" ::: "memory");
    __builtin_amdgcn_sched_barrier(0);
    __builtin_amdgcn_s_barrier();
    __builtin_amdgcn_sched_barrier(0);
    if (kt < 14) stage(cur, (kt + 2) * 64);
  }

  // ---- epilogue part 1: L2-norm reduce; stage pwT (over dead Xs[0]) in parallel ----
  float* pwT   = (float*)pool;             // [256][20]: [c][l<16]=pw[l][c], [c][16]=cw[c]
  float* redp  = (float*)(pool + 32768);   // [4][2][2][17][16]
  float* ssred = (float*)(pool + 65536);   // [4][64]
  float* rinvp = (float*)(pool + 66560);   // [64]

  float ss0 = 0.f, ss1 = 0.f;
  #pragma unroll
  for (int fm = 0; fm < 4; ++fm)
    #pragma unroll
    for (int r = 0; r < 4; ++r){
      ss0 += acc[fm][0][r] * acc[fm][0][r];
      ss1 += acc[fm][1][r] * acc[fm][1][r];
    }
  ss0 += __shfl_xor(ss0, 16); ss0 += __shfl_xor(ss0, 32);
  ss1 += __shfl_xor(ss1, 16); ss1 += __shfl_xor(ss1, 32);
  if (l < 16){
    ssred[wr * 64 + wc * 32 + l]      = ss0;
    ssred[wr * 64 + wc * 32 + 16 + l] = ss1;
  }

  if (!last){
    const float* __restrict__ pw = g ? pw2 : pw1;
    const float* __restrict__ cw = g ? cw2 : cw1;
    // pw: 4096 floats -> 8 per thread (two float4 from row lq, cols c..c+7)
    {
      const int idx = t * 8;
      const int lq = idx >> 8, c = idx & 255;
      const float4 p0 = *(const float4*)&pw[lq * C_ + c];
      const float4 p1 = *(const float4*)&pw[lq * C_ + c + 4];
      pwT[(c + 0) * 20 + lq] = p0.x; pwT[(c + 1) * 20 + lq] = p0.y;
      pwT[(c + 2) * 20 + lq] = p0.z; pwT[(c + 3) * 20 + lq] = p0.w;
      pwT[(c + 4) * 20 + lq] = p1.x; pwT[(c + 5) * 20 + lq] = p1.y;
      pwT[(c + 6) * 20 + lq] = p1.z; pwT[(c + 7) * 20 + lq] = p1.w;
    }
    if (t < 32){
      const float4 c0 = *(const float4*)&cw[t * 8];
      const float4 c1 = *(const float4*)&cw[t * 8 + 4];
      pwT[(t * 8 + 0) * 20 + 16] = c0.x; pwT[(t * 8 + 1) * 20 + 16] = c0.y;
      pwT[(t * 8 + 2) * 20 + 16] = c0.z; pwT[(t * 8 + 3) * 20 + 16] = c0.w;
      pwT[(t * 8 + 4) * 20 + 16] = c1.x; pwT[(t * 8 + 5) * 20 + 16] = c1.y;
      pwT[(t * 8 + 6) * 20 + 16] = c1.z; pwT[(t * 8 + 7) * 20 + 16] = c1.w;
    }
  }
  __syncthreads();
  if (t < 64){
    const float s = ssred[t] + ssred[64 + t] + ssred[128 + t] + ssred[192 + t];
    rinvp[t] = 1.f / fmaxf(sqrtf(s), 1e-12f);
  }
  __syncthreads();
  const float ri[2] = { rinvp[wc * 32 + (l & 15)], rinvp[wc * 32 + 16 + (l & 15)] };

  // ---- epilogue part 2: per-element h / residual / ReLU + sa-dot accumulation ----
  const float* __restrict__ fpin = (g ? fpin2 : fpin1) + (size_t)n * C_ * HW_;
  float* __restrict__ fpo  = (g ? fpo2 : fpo1) + (size_t)n * C_ * HW_;
  _Float16* __restrict__ fhn = (g ? fhn2 : fhn1) + (size_t)n * C_ * HW_;
  float* __restrict__ outp = out + (size_t)g * SZ_ + (size_t)n * C_ * HW_;
  const int rbase = (l >> 4) * 4, col = l & 15;
  const int baseio = n * 2 + g;

  if (!last){
    float sacc[2][17];
    #pragma unroll
    for (int fn = 0; fn < 2; ++fn)
      #pragma unroll
      for (int lq = 0; lq < 17; ++lq) sacc[fn][lq] = 0.f;

    #pragma unroll
    for (int fm = 0; fm < 4; ++fm)
      #pragma unroll
      for (int r = 0; r < 4; ++r){
        const int c = wr * 64 + fm * 16 + rbase + r;
        float prow[17];
        #pragma unroll
        for (int q4 = 0; q4 < 4; ++q4){
          const float4 pv = *(const float4*)&pwT[c * 20 + q4 * 4];
          prow[q4 * 4 + 0] = pv.x; prow[q4 * 4 + 1] = pv.y;
          prow[q4 * 4 + 2] = pv.z; prow[q4 * 4 + 3] = pv.w;
        }
        prow[16] = pwT[c * 20 + 16];
        #pragma unroll
        for (int fn = 0; fn < 2; ++fn){
          const size_t base = (size_t)c * HW_ + i0 + wc * 32 + fn * 16 + col;
          const float h = acc[fm][fn][r] * ri[fn];
          const float fv = fpin[base] + h;
          const float rv = fv > 0.f ? fv : 0.f;
          fpo[base] = rv;
          fhn[base] = (_Float16)rv;
          #pragma unroll
          for (int lq = 0; lq < 17; ++lq) sacc[fn][lq] += rv * prow[lq];
        }
      }

    // reduce over l>>4 within wave, then across (wr) via LDS
    #pragma unroll
    for (int fn = 0; fn < 2; ++fn)
      #pragma unroll
      for (int lq = 0; lq < 17; ++lq){
        float v = sacc[fn][lq];
        v += __shfl_xor(v, 16);
        v += __shfl_xor(v, 32);
        sacc[fn][lq] = v;
      }
    if (l < 16){
      #pragma unroll
      for (int fn = 0; fn < 2; ++fn)
        #pragma unroll
        for (int lq = 0; lq < 17; ++lq)
          redp[(((wr * 2 + wc) * 2 + fn) * 17 + lq) * 16 + l] = sacc[fn][lq];
    }
    __syncthreads();
    if (t < 64){
      const int wcx = t >> 5, fnx = (t >> 4) & 1, colx = t & 15;
      float xc = 0.f;
      #pragma unroll
      for (int lq = 0; lq < 17; ++lq){
        float s = 0.f;
        #pragma unroll
        for (int wrx = 0; wrx < 4; ++wrx)
          s += redp[(((wrx * 2 + wcx) * 2 + fnx) * 17 + lq) * 16 + colx];
        if (lq < 16) pdot[((size_t)baseio * CL_ + lq) * HW_ + i0 + t] = s;
        else       { cval[(size_t)baseio * HW_ + i0 + t] = s; xc = s; }
      }
      float mb = xc;
      #pragma unroll
      for (int off = 32; off; off >>= 1) mb = fmaxf(mb, __shfl_xor(mb, off));
      float e = __expf(xc - mb);
      #pragma unroll
      for (int off = 32; off; off >>= 1) e += __shfl_xor(e, off);
      if (t == 0){
        mpart[baseio * 16 + (i0 >> 6)] = mb;
        spart[baseio * 16 + (i0 >> 6)] = e;
      }
    }
  } else {
    #pragma unroll
    for (int fm = 0; fm < 4; ++fm)
      #pragma unroll
      for (int fn = 0; fn < 2; ++fn){
        const size_t base = (size_t)(wr * 64 + fm * 16 + rbase) * HW_ + i0 + wc * 32 + fn * 16 + col;
        #pragma unroll
        for (int r = 0; r < 4; ++r)
          outp[base + (size_t)r * HW_] = acc[fm][fn][r] * ri[fn];
      }
  }
}

// K_s: s[n,c,hw] = w * fp (fp32 state),  w = exp(cval - m) * rl
__global__ __launch_bounds__(256) void k_s_out(
    const float* __restrict__ fp1, const float* __restrict__ fp2,
    const float* __restrict__ cval,
    const float* __restrict__ mpart, const float* __restrict__ spart,
    float* __restrict__ out)
{
  const int side = blockIdx.y;
  const size_t fo = ((size_t)blockIdx.x * 256 + threadIdx.x) * 4;
  const float* __restrict__ f = side ? fp2 : fp1;
  const int n  = (int)(fo >> 18);
  const int hw = (int)(fo & (HW_ - 1));
  const int base = n * 2 + side;
  float m, rl;
  combine16(mpart, spart, base, m, rl);
  const float4 c = *(const float4*)&cval[(size_t)base * HW_ + hw];
  const float4 v = *(const float4*)&f[fo];
  float4 r;
  r.x = v.x * (__expf(c.x - m) * rl);
  r.y = v.y * (__expf(c.y - m) * rl);
  r.z = v.z * (__expf(c.z - m) * rl);
  r.w = v.w * (__expf(c.w - m) * rl);
  *(float4*)&out[(size_t)(2 + side) * SZ_ + fo] = r;
}

extern "C" void kernel_launch(void* const* d_in, const int* in_sizes, int n_in,
                              void* d_out, int out_size, void* d_ws, size_t ws_size,
                              hipStream_t stream)
{
  const float* f1  = (const float*)d_in[0];
  const float* f2  = (const float*)d_in[1];
  const float* pw1 = (const float*)d_in[2];
  const float* pb1 = (const float*)d_in[3];
  const float* pw2 = (const float*)d_in[4];
  const float* pb2 = (const float*)d_in[5];
  const float* cw1 = (const float*)d_in[6];
  const float* cw2 = (const float*)d_in[8];
  // cb1/cb2 unused: softmax is shift-invariant
  float* out = (float*)d_out;
  float* ws  = (float*)d_ws;

  float* cval  = ws;                           // 16K f32
  float* pdot  = cval + N_ * 2 * HW_;          // 256K f32
  float* mpart = pdot + N_ * 2 * CL_ * HW_;    // 512
  float* spart = mpart + 512;                  // 512
  float* fp1   = spart + 512;                  // SZ_ f32 state
  float* fp2   = fp1 + SZ_;                    // SZ_ f32 state
  _Float16* fhA1 = (_Float16*)(fp2 + SZ_);     // SZ_ fp16 mirror (ping)
  _Float16* fhA2 = fhA1 + SZ_;
  _Float16* fhB1 = fhA2 + SZ_;                 // SZ_ fp16 mirror (pong)
  _Float16* fhB2 = fhB1 + SZ_;
  unsigned short* Abf  = (unsigned short*)(fhB2 + SZ_);  // 8M fp16
  unsigned short* Atbf = Abf + ((size_t)N_ << 20);       // 8M fp16

  k_cvt<<<dim3(SZ_ / 8 / 256, 2), 256, 0, stream>>>(f1, f2, fhA1, fhA2);
  k_sa_dot<<<dim3(16, 2, 8), 256, 0, stream>>>(f1, f2, cw1, cw2, pw1, pw2,
                                               cval, pdot, mpart, spart);

  for (int it = 0; it < 5; ++it){
    const float* cur1 = (it == 0) ? f1 : fp1;
    const float* cur2 = (it == 0) ? f2 : fp2;
    const _Float16* fhc1 = (it & 1) ? fhB1 : fhA1;
    const _Float16* fhc2 = (it & 1) ? fhB2 : fhA2;
    _Float16* fhn1 = (it & 1) ? fhA1 : fhB1;
    _Float16* fhn2 = (it & 1) ? fhA2 : fhB2;

    k_corr<<<dim3(16, 16, 8), 256, 0, stream>>>(cval, pdot, pb1, pb2, mpart, spart, Abf, Atbf);
    if (it == 4)
      k_s_out<<<dim3(SZ_ / 4 / 256, 2), 256, 0, stream>>>(cur1, cur2, cval, mpart, spart, out);
    k_gemm_fused<<<dim3(16, 2, 8), 512, 0, stream>>>(fhc1, fhc2, Abf, Atbf,
                                                     cur1, cur2, fp1, fp2, fhn1, fhn2,
                                                     pw1, pw2, cw1, cw2,
                                                     cval, pdot, mpart, spart,
                                                     out, (it == 4) ? 1 : 0);
  }
}